// Round 1
// baseline (91.617 us; speedup 1.0000x reference)
//
#include <hip/hip_runtime.h>

#define NBINS 15
#define NTHREADS 256
#define NWAVES 4          // 256 / 64
#define NBLOCKS 1024      // 4 blocks/CU on 256 CUs

// Kernel 1: streaming pass. Each thread scatters into its OWN LDS slots
// lds[wave][bin][lane] (bank = lane%32 -> 2 lanes/bank = conflict-free).
// Block reduces to 30 partial sums (15 conf, 15 acc) written to d_ws.
__global__ __launch_bounds__(NTHREADS) void ece_partial_kernel(
    const float* __restrict__ logits,
    const int* __restrict__ labels,
    float* __restrict__ partials,
    int n)
{
    __shared__ float conf_lds[NWAVES][NBINS][64];
    __shared__ float accs_lds[NWAVES][NBINS][64];
    __shared__ float wavesum[2][NWAVES][NBINS];

    const int tid  = threadIdx.x;
    const int lane = tid & 63;
    const int w    = tid >> 6;

    // zero own slots (no barrier needed: exclusive ownership)
    #pragma unroll
    for (int b = 0; b < NBINS; ++b) {
        conf_lds[w][b][lane] = 0.0f;
        accs_lds[w][b][lane] = 0.0f;
    }

    const int n4 = n >> 2;
    const float4* L4 = (const float4*)logits;
    const int4*   Y4 = (const int4*)labels;
    const int stride = NBLOCKS * NTHREADS;

    for (int i = blockIdx.x * NTHREADS + tid; i < n4; i += stride) {
        float4 x = L4[i];
        int4   y = Y4[i];
        #pragma unroll
        for (int j = 0; j < 4; ++j) {
            float xv = (&x.x)[j];
            int   yv = (&y.x)[j];
            float p = 1.0f / (1.0f + __expf(-xv));
            // digitize(p, linspace(0,1,16), right=True)-1 == ceil(p*15)-1 for p in (0,1]
            int b = (int)ceilf(p * 15.0f) - 1;
            b = min(max(b, 0), NBINS - 1);
            if (p > 0.0f) {           // valid = p > 0 (matches reference)
                bool pred = p > 0.5f;
                float a = (pred == (yv != 0)) ? 1.0f : 0.0f;
                conf_lds[w][b][lane] += p;
                accs_lds[w][b][lane] += a;
            }
        }
    }

    // scalar tail (n not a multiple of 4) — block 0 only
    if (blockIdx.x == 0) {
        for (int i = (n4 << 2) + tid; i < n; i += NTHREADS) {
            float xv = logits[i];
            int   yv = labels[i];
            float p = 1.0f / (1.0f + __expf(-xv));
            int b = (int)ceilf(p * 15.0f) - 1;
            b = min(max(b, 0), NBINS - 1);
            if (p > 0.0f) {
                bool pred = p > 0.5f;
                float a = (pred == (yv != 0)) ? 1.0f : 0.0f;
                conf_lds[w][b][lane] += p;
                accs_lds[w][b][lane] += a;
            }
        }
    }

    __syncthreads();

    // per-wave butterfly reduce across the 64-lane dimension
    #pragma unroll
    for (int b = 0; b < NBINS; ++b) {
        float c = conf_lds[w][b][lane];
        float a = accs_lds[w][b][lane];
        #pragma unroll
        for (int m = 32; m >= 1; m >>= 1) {
            c += __shfl_xor(c, m, 64);
            a += __shfl_xor(a, m, 64);
        }
        if (lane == 0) { wavesum[0][w][b] = c; wavesum[1][w][b] = a; }
    }
    __syncthreads();

    if (tid < 2 * NBINS) {
        const int arr = tid / NBINS;
        const int b   = tid % NBINS;
        float s = 0.0f;
        #pragma unroll
        for (int ww = 0; ww < NWAVES; ++ww) s += wavesum[arr][ww][b];
        partials[blockIdx.x * (2 * NBINS) + tid] = s;
    }
}

// Kernel 2: deterministic fixed-order reduction of NBLOCKS x 30 partials,
// then ece = sum_b |conf_b - acc_b| / n.
__global__ __launch_bounds__(NTHREADS) void ece_final_kernel(
    const float* __restrict__ partials,
    float* __restrict__ out,
    float inv_n)
{
    __shared__ double red[2 * NBINS];
    const int t = threadIdx.x;
    if (t < 8 * 2 * NBINS) {          // 240 threads: 8 per (arr,bin) job
        const int j   = t >> 3;       // 0..29
        const int sub = t & 7;
        double s = 0.0;
        for (int k = sub; k < NBLOCKS; k += 8)
            s += (double)partials[k * (2 * NBINS) + j];
        s += __shfl_xor(s, 4, 8);
        s += __shfl_xor(s, 2, 8);
        s += __shfl_xor(s, 1, 8);
        if (sub == 0) red[j] = s;
    }
    __syncthreads();
    if (t == 0) {
        double e = 0.0;
        #pragma unroll
        for (int b = 0; b < NBINS; ++b)
            e += fabs(red[b] - red[NBINS + b]);
        out[0] = (float)(e * (double)inv_n);
    }
}

extern "C" void kernel_launch(void* const* d_in, const int* in_sizes, int n_in,
                              void* d_out, int out_size, void* d_ws, size_t ws_size,
                              hipStream_t stream)
{
    const float* logits = (const float*)d_in[0];
    const int*   labels = (const int*)d_in[1];
    float* out      = (float*)d_out;
    float* partials = (float*)d_ws;   // NBLOCKS * 30 * 4 B = 120 KiB
    const int n = in_sizes[0];

    ece_partial_kernel<<<NBLOCKS, NTHREADS, 0, stream>>>(logits, labels, partials, n);
    ece_final_kernel<<<1, NTHREADS, 0, stream>>>(partials, out, 1.0f / (float)n);
}